// Round 6
// baseline (187.867 us; speedup 1.0000x reference)
//
#include <hip/hip_runtime.h>
#include <hip/hip_fp16.h>

#define TSTEPS 4
#define DIM 32
#define BINW_SHIFT 8          // 256 nodes per coarse bin
#define NB 256                // bins (actual 196, rest zero)
#define SP_CH 2048            // edges per chunk (hist & split use same chunking)
#define PAD_PER_BIN 772       // worst-case rec padding per bin (256*3 + 4)

typedef _Float16 f16x8 __attribute__((ext_vector_type(8)));
typedef float f32x4 __attribute__((ext_vector_type(4)));

// load 8 consecutive halfs (16B, aligned) -> two float4
__device__ __forceinline__ void ldx8h(const __half* p, float4& lo, float4& hi) {
    uint4 u = *(const uint4*)p;
    __half2 h0 = *(__half2*)&u.x;
    __half2 h1 = *(__half2*)&u.y;
    __half2 h2 = *(__half2*)&u.z;
    __half2 h3 = *(__half2*)&u.w;
    float2 a = __half22float2(h0);
    float2 b = __half22float2(h1);
    float2 c = __half22float2(h2);
    float2 d = __half22float2(h3);
    lo = make_float4(a.x, a.y, b.x, b.y);
    hi = make_float4(c.x, c.y, d.x, d.y);
}

// ---- K0: per-node degree (800K global atomics over 200KB, L2-resident) ----
__global__ __launch_bounds__(256) void deg_kernel(
    const int* __restrict__ ei, int* __restrict__ deg, int E) {
    int stride = gridDim.x * 256;
    for (int e = blockIdx.x * 256 + threadIdx.x; e < E; e += stride)
        atomicAdd(&deg[ei[E + e]], 1);
}

// ---- K1: per-chunk coarse histogram (blocks [0,nchunks)) + MFMA GEMM ----
// GEMM computes xws = dinv .* (s @ W) via swapped-operand mfma so each lane
// owns 4 CONSECUTIVE features of one row -> two 8B packed stores per tile.
__global__ __launch_bounds__(256) void histgemm_kernel(
    const int* __restrict__ ei, int* __restrict__ ghist,
    const float* __restrict__ s, const float* __restrict__ W,
    const int* __restrict__ deg, __half* __restrict__ xwp,
    int E, int rows, int N, int nchunks) {
    __shared__ float Wf[32][33];   // 4.2 KB; hist role reuses first 1 KB
    int tid = threadIdx.x;

    if ((int)blockIdx.x < nchunks) {
        int* lh = (int*)Wf;
        lh[tid] = 0;
        __syncthreads();
        int beg = blockIdx.x * SP_CH;
        int end = min(beg + SP_CH, E);
        for (int e = beg + tid; e < end; e += 256)
            atomicAdd(&lh[ei[E + e] >> BINW_SHIFT], 1);
        __syncthreads();
        ghist[(size_t)blockIdx.x * NB + tid] = lh[tid];
        return;
    }

    // ---- GEMM role ----
    {
        float4 wv = ((const float4*)W)[tid];
        int kk = tid >> 3, c4 = (tid & 7) * 4;
        Wf[kk][c4 + 0] = wv.x; Wf[kk][c4 + 1] = wv.y;
        Wf[kk][c4 + 2] = wv.z; Wf[kk][c4 + 3] = wv.w;
    }
    __syncthreads();

    int lane = tid & 63;
    int wid  = tid >> 6;          // 0..3
    int lrow = lane & 15;
    int kq   = lane >> 4;         // k-group 0..3
    int k0   = kq * 8;

    // frags: b holds W[k0..k0+7][col] (used as MFMA *A* operand = W^T rows)
    f16x8 b0, b1;
#pragma unroll
    for (int i = 0; i < 8; i++) {
        b0[i] = (_Float16)Wf[k0 + i][lrow];
        b1[i] = (_Float16)Wf[k0 + i][lrow + 16];
    }

    int rbase = ((int)blockIdx.x - nchunks) * 128 + wid * 32;
#pragma unroll
    for (int rt = 0; rt < 2; rt++) {
        int r = rbase + rt * 16 + lrow;
        f16x8 a;
        if (r < rows) {
            const float4* sp = (const float4*)(s + (size_t)r * 32 + k0);
            float4 u0 = sp[0], u1 = sp[1];
            a[0] = (_Float16)u0.x; a[1] = (_Float16)u0.y;
            a[2] = (_Float16)u0.z; a[3] = (_Float16)u0.w;
            a[4] = (_Float16)u1.x; a[5] = (_Float16)u1.y;
            a[6] = (_Float16)u1.z; a[7] = (_Float16)u1.w;
        } else {
#pragma unroll
            for (int i = 0; i < 8; i++) a[i] = (_Float16)0.f;
        }
        // Swapped operands: D = (W^T)(s^T) = (sW)^T.
        // D col (lane&15) = s-row within tile (== lrow of the a just loaded),
        // D row (kq*4+reg) = feature -> 4 consecutive features per lane.
        f32x4 c0 = {0.f, 0.f, 0.f, 0.f};
        f32x4 c1 = {0.f, 0.f, 0.f, 0.f};
        c0 = __builtin_amdgcn_mfma_f32_16x16x32_f16(b0, a, c0, 0, 0, 0);
        c1 = __builtin_amdgcn_mfma_f32_16x16x32_f16(b1, a, c1, 0, 0, 0);
        if (r < rows) {
            int t = (r >= 3 * N) ? 3 : (r >= 2 * N) ? 2 : (r >= N) ? 1 : 0;
            int n = r - t * N;
            float di = rsqrtf((float)deg[n] + 1.0f);
            __half2 p0 = __floats2half2_rn(c0[0] * di, c0[1] * di);
            __half2 p1 = __floats2half2_rn(c0[2] * di, c0[3] * di);
            __half2 p2 = __floats2half2_rn(c1[0] * di, c1[1] * di);
            __half2 p3 = __floats2half2_rn(c1[2] * di, c1[3] * di);
            __half* dst = xwp + (size_t)n * 128 + t * 32;
            uint2 u0, u1;
            u0.x = *(unsigned int*)&p0; u0.y = *(unsigned int*)&p1;
            u1.x = *(unsigned int*)&p2; u1.y = *(unsigned int*)&p3;
            *(uint2*)(dst + kq * 4)      = u0;
            *(uint2*)(dst + 16 + kq * 4) = u1;
        }
    }
}

// ---- K2: transposed scan over chunks per bin ----
__global__ __launch_bounds__(512) void colscan_kernel(
    const int* __restrict__ ghist, int* __restrict__ ghist2,
    int* __restrict__ totals, int nchunks) {
    __shared__ int sc[512];
    int t = threadIdx.x;
    int b = blockIdx.x;
    int v = (t < nchunks) ? ghist[(size_t)t * NB + b] : 0;
    sc[t] = v;
    __syncthreads();
    for (int off = 1; off < 512; off <<= 1) {
        int tv = (t >= off) ? sc[t - off] : 0;
        __syncthreads();
        sc[t] += tv;
        __syncthreads();
    }
    if (t < nchunks) ghist2[(size_t)t * NB + b] = sc[t] - v;   // exclusive
    if (t == 511) totals[b] = sc[511];
}

// ---- K3: split with exact precomputed bases ----
__global__ __launch_bounds__(256) void split_kernel(
    const int* __restrict__ ei, const int* __restrict__ ghist,
    const int* __restrict__ ghist2, const int* __restrict__ totals,
    unsigned int* __restrict__ esorted, int E) {
    __shared__ int binB[NB], pscan[NB], gb[NB], pcur[NB];
    __shared__ unsigned int sbuf[SP_CH];
    int tid = threadIdx.x;
    int bid = blockIdx.x;

    int tot = totals[tid];
    binB[tid] = tot;
    __syncthreads();
    for (int off = 1; off < 256; off <<= 1) {
        int t = (tid >= off) ? binB[tid - off] : 0;
        __syncthreads();
        binB[tid] += t;
        __syncthreads();
    }
    int v = ghist[(size_t)bid * NB + tid];
    pscan[tid] = v;
    __syncthreads();
    for (int off = 1; off < 256; off <<= 1) {
        int t = (tid >= off) ? pscan[tid - off] : 0;
        __syncthreads();
        pscan[tid] += t;
        __syncthreads();
    }
    int pexcl = pscan[tid] - v;
    pscan[tid] = pexcl;
    pcur[tid] = pexcl;
    gb[tid] = (binB[tid] - tot) + ghist2[(size_t)bid * NB + tid] - pexcl;
    __syncthreads();

    int beg = bid * SP_CH;
    int end = min(beg + SP_CH, E);
    int cnt = end - beg;
    for (int e = beg + tid; e < end; e += 256) {
        int sx = ei[e];
        int dx = ei[E + e];
        unsigned int pk = (unsigned int)sx | ((unsigned int)dx << 16);
        int b = dx >> BINW_SHIFT;
        int p = atomicAdd(&pcur[b], 1);
        sbuf[p] = pk;
    }
    __syncthreads();
    for (int idx = tid; idx < cnt; idx += 256) {
        unsigned int e = sbuf[idx];
        int b = e >> 24;                 // dst>>8 (dst in bits 16..31)
        esorted[gb[b] + idx] = e;
    }
}

// ---- K4: per-bin exact CSR (writes offs + dinv; deg comes from K0) ----
__global__ __launch_bounds__(256) void csr_kernel(
    const int* __restrict__ totals, const unsigned int* __restrict__ esorted,
    int* __restrict__ rec, int* __restrict__ offs,
    float* __restrict__ dinv, int N) {
    __shared__ int lh[NB], sc[NB], loff[NB], lcur[NB];
    __shared__ int s_ebeg, s_cnt;
    int bin = blockIdx.x;
    int tid = threadIdx.x;
    sc[tid] = totals[tid];
    lh[tid] = 0;
    __syncthreads();
    for (int off = 1; off < 256; off <<= 1) {
        int t = (tid >= off) ? sc[tid - off] : 0;
        __syncthreads();
        sc[tid] += t;
        __syncthreads();
    }
    if (tid == 0) {
        int e0 = bin ? sc[bin - 1] : 0;
        s_ebeg = e0;
        s_cnt = sc[bin] - e0;
    }
    __syncthreads();
    int ebeg = s_ebeg;
    int cnt = s_cnt;
    int gbase = ((ebeg + 3) & ~3) + PAD_PER_BIN * bin;
    for (int i = tid; i < cnt; i += 256)
        atomicAdd(&lh[(esorted[ebeg + i] >> 16) & 255], 1);
    __syncthreads();
    int padded = (lh[tid] + 3) & ~3;
    sc[tid] = padded;
    __syncthreads();
    for (int off = 1; off < 256; off <<= 1) {
        int t = (tid >= off) ? sc[tid - off] : 0;
        __syncthreads();
        sc[tid] += t;
        __syncthreads();
    }
    loff[tid] = sc[tid] - padded;
    lcur[tid] = 0;
    __syncthreads();
    for (int i = tid; i < cnt; i += 256) {
        unsigned int e = esorted[ebeg + i];
        int ln = (e >> 16) & 255;
        int p = atomicAdd(&lcur[ln], 1);
        rec[gbase + loff[ln] + p] = (int)(e & 0xFFFFu);
    }
    int n = (bin << BINW_SHIFT) + tid;
    if (n < N) {
        offs[n] = gbase + loff[tid];
        dinv[n] = rsqrtf((float)lh[tid] + 1.0f);
    }
}

// ---- K5: fused gather over PRE-SCALED xwp: acc = dinv[n]*(sum rows + self),
// no per-edge dinv loads, FMAs become adds. 16 lanes/node x dwordx4. ----
__global__ __launch_bounds__(256) void gather_kernel(
    const int* __restrict__ rec, const int* __restrict__ offs,
    const int* __restrict__ deg, const __half* __restrict__ xwp,
    const float* __restrict__ dinv, const float* __restrict__ z,
    float* __restrict__ out, int N) {
    int gid = blockIdx.x * 256 + threadIdx.x;
    int n = gid >> 4;
    if (n >= N) return;
    int wl = threadIdx.x & 63;
    int g = wl >> 4;          // node slot in wave (0..3)
    int l = wl & 15;          // lane within node
    long lofs = (long)l * 8;  // offset in halfs (16B per lane)

    float dn = dinv[n];
    int beg = offs[n];        // multiple of 4 -> int4-aligned
    int cntn = deg[n];

    float4 aLo = make_float4(0.f, 0.f, 0.f, 0.f);
    float4 aHi = make_float4(0.f, 0.f, 0.f, 0.f);
    int i = 0;
    for (; i + 8 <= cntn; i += 8) {
        int4 sa = *(const int4*)(rec + beg + i);
        int4 sb = *(const int4*)(rec + beg + i + 4);
        float4 l0, h0, l1, h1, l2, h2, l3, h3;
        float4 l4, h4, l5, h5, l6, h6, l7, h7;
        ldx8h(xwp + (long)sa.x * 128 + lofs, l0, h0);
        ldx8h(xwp + (long)sa.y * 128 + lofs, l1, h1);
        ldx8h(xwp + (long)sa.z * 128 + lofs, l2, h2);
        ldx8h(xwp + (long)sa.w * 128 + lofs, l3, h3);
        ldx8h(xwp + (long)sb.x * 128 + lofs, l4, h4);
        ldx8h(xwp + (long)sb.y * 128 + lofs, l5, h5);
        ldx8h(xwp + (long)sb.z * 128 + lofs, l6, h6);
        ldx8h(xwp + (long)sb.w * 128 + lofs, l7, h7);
        aLo.x += (l0.x + l1.x) + (l2.x + l3.x) + (l4.x + l5.x) + (l6.x + l7.x);
        aLo.y += (l0.y + l1.y) + (l2.y + l3.y) + (l4.y + l5.y) + (l6.y + l7.y);
        aLo.z += (l0.z + l1.z) + (l2.z + l3.z) + (l4.z + l5.z) + (l6.z + l7.z);
        aLo.w += (l0.w + l1.w) + (l2.w + l3.w) + (l4.w + l5.w) + (l6.w + l7.w);
        aHi.x += (h0.x + h1.x) + (h2.x + h3.x) + (h4.x + h5.x) + (h6.x + h7.x);
        aHi.y += (h0.y + h1.y) + (h2.y + h3.y) + (h4.y + h5.y) + (h6.y + h7.y);
        aHi.z += (h0.z + h1.z) + (h2.z + h3.z) + (h4.z + h5.z) + (h6.z + h7.z);
        aHi.w += (h0.w + h1.w) + (h2.w + h3.w) + (h4.w + h5.w) + (h6.w + h7.w);
    }
    for (; i < cntn; i += 4) {
        int4 s4 = *(const int4*)(rec + beg + i);
        int rem = cntn - i;
        int i0 = s4.x;
        int i1 = (rem > 1) ? s4.y : i0;
        int i2 = (rem > 2) ? s4.z : i0;
        int i3 = (rem > 3) ? s4.w : i0;
        float w1 = (rem > 1) ? 1.f : 0.f;
        float w2 = (rem > 2) ? 1.f : 0.f;
        float w3 = (rem > 3) ? 1.f : 0.f;
        float4 l0, h0, l1, h1, l2, h2, l3, h3;
        ldx8h(xwp + (long)i0 * 128 + lofs, l0, h0);
        ldx8h(xwp + (long)i1 * 128 + lofs, l1, h1);
        ldx8h(xwp + (long)i2 * 128 + lofs, l2, h2);
        ldx8h(xwp + (long)i3 * 128 + lofs, l3, h3);
        aLo.x += l0.x + w1 * l1.x + w2 * l2.x + w3 * l3.x;
        aLo.y += l0.y + w1 * l1.y + w2 * l2.y + w3 * l3.y;
        aLo.z += l0.z + w1 * l1.z + w2 * l2.z + w3 * l3.z;
        aLo.w += l0.w + w1 * l1.w + w2 * l2.w + w3 * l3.w;
        aHi.x += h0.x + w1 * h1.x + w2 * h2.x + w3 * h3.x;
        aHi.y += h0.y + w1 * h1.y + w2 * h2.y + w3 * h3.y;
        aHi.z += h0.z + w1 * h1.z + w2 * h2.z + w3 * h3.z;
        aHi.w += h0.w + w1 * h1.w + w2 * h2.w + w3 * h3.w;
    }
    // self loop (xwp pre-scaled: contributes dinv[n]*xw[n] after final *dn)
    {
        float4 sl, sh;
        ldx8h(xwp + (long)n * 128 + lofs, sl, sh);
        aLo.x += sl.x; aLo.y += sl.y; aLo.z += sl.z; aLo.w += sl.w;
        aHi.x += sh.x; aHi.y += sh.y; aHi.z += sh.z; aHi.w += sh.w;
    }
    aLo.x *= dn; aLo.y *= dn; aLo.z *= dn; aLo.w *= dn;
    aHi.x *= dn; aHi.y *= dn; aHi.z *= dn; aHi.w *= dn;

    // Lane l holds halfs l*8..l*8+7 (t = l>>2, feature block (l&3)*8).
    float a8[8] = {aLo.x, aLo.y, aLo.z, aLo.w, aHi.x, aHi.y, aHi.z, aHi.w};
    float xs[TSTEPS][8];
    int base = g * 16;
#pragma unroll
    for (int t = 0; t < TSTEPS; t++) {
        int srcLane = base + t * 4 + l;
#pragma unroll
        for (int j = 0; j < 8; j++)
            xs[t][j] = __shfl(a8[j], srcLane, 64);
    }
    if (l < 4) {
        int colBase = n * 32 + l * 8;
        float v[8], y[8];
#pragma unroll
        for (int j = 0; j < 8; j++) {
            v[j] = 0.f;
            y[j] = (xs[0][j] + xs[1][j] + xs[2][j] + xs[3][j]) * 0.25f;
        }
#pragma unroll
        for (int t = 0; t < TSTEPS; t++) {
            float o[8];
#pragma unroll
            for (int j = 0; j < 8; j++) {
                v[j] += xs[t][j];
                o[j] = (v[j] >= 1.0f) ? 1.0f : 0.0f;
                v[j] -= o[j];
            }
            float* dst = out + (size_t)t * N * 32 + colBase;
            *(float4*)dst       = make_float4(o[0], o[1], o[2], o[3]);
            *(float4*)(dst + 4) = make_float4(o[4], o[5], o[6], o[7]);
        }
        float4 zv0 = *(const float4*)(z + colBase);
        float4 zv1 = *(const float4*)(z + colBase + 4);
        float* dst = out + (size_t)TSTEPS * N * 32 + colBase;
        *(float4*)dst       = make_float4(zv0.x + y[0], zv0.y + y[1], zv0.z + y[2], zv0.w + y[3]);
        *(float4*)(dst + 4) = make_float4(zv1.x + y[4], zv1.y + y[5], zv1.z + y[6], zv1.w + y[7]);
    }
}

extern "C" void kernel_launch(void* const* d_in, const int* in_sizes, int n_in,
                              void* d_out, int out_size, void* d_ws, size_t ws_size,
                              hipStream_t stream) {
    const float* s_seq = (const float*)d_in[0];
    const float* z_seq = (const float*)d_in[1];
    const float* W     = (const float*)d_in[2];
    const int*   ei    = (const int*)d_in[3];
    float* out = (float*)d_out;

    int N = in_sizes[1] / DIM;   // 50000
    int E = in_sizes[3] / 2;     // 800000
    int rows = TSTEPS * N;       // 200000
    int nb = (N + 255) >> BINW_SHIFT;        // 196
    int nchunks = (E + SP_CH - 1) / SP_CH;   // 391

    char* w = (char*)d_ws;
    __half* xwp           = (__half*)w;       w += (size_t)rows * DIM * 2;   // 12.8 MB
    unsigned int* esorted = (unsigned int*)w; w += (size_t)E * 4;            // 3.2 MB
    int*   rec    = (int*)w;  w += ((size_t)E + PAD_PER_BIN * nb + 16) * 4;  // 3.8 MB
    int*   offs   = (int*)w;  w += (size_t)N * 4;
    int*   deg    = (int*)w;  w += (size_t)N * 4;
    float* dinv   = (float*)w; w += (size_t)N * 4;
    int*   ghist  = (int*)w;  w += (size_t)nchunks * NB * 4;                 // 400 KB
    int*   ghist2 = (int*)w;  w += (size_t)nchunks * NB * 4;                 // 400 KB
    int*   totals = (int*)w;  w += NB * 4;

    hipMemsetAsync(deg, 0, (size_t)N * 4, stream);

    int xwBlocks = (rows + 127) / 128;   // 1563
    deg_kernel<<<512, 256, 0, stream>>>(ei, deg, E);
    histgemm_kernel<<<nchunks + xwBlocks, 256, 0, stream>>>(
        ei, ghist, s_seq, W, deg, xwp, E, rows, N, nchunks);
    colscan_kernel<<<NB, 512, 0, stream>>>(ghist, ghist2, totals, nchunks);
    split_kernel<<<nchunks, 256, 0, stream>>>(ei, ghist, ghist2, totals, esorted, E);
    csr_kernel<<<nb, 256, 0, stream>>>(totals, esorted, rec, offs, dinv, N);
    gather_kernel<<<(N * 16 + 255) / 256, 256, 0, stream>>>(rec, offs, deg, xwp,
                                                            dinv, z_seq, out, N);
}

// Round 7
// 154.234 us; speedup vs baseline: 1.2181x; 1.2181x over previous
//
#include <hip/hip_runtime.h>
#include <hip/hip_fp16.h>

#define TSTEPS 4
#define DIM 32
#define BINW_SHIFT 8          // 256 nodes per coarse bin
#define NB 256                // bins (actual 196, rest zero)
#define SP_CH 2048            // edges per chunk (hist & split use same chunking)
#define PAD_PER_BIN 772       // worst-case rec padding per bin (256*3 + 4)

typedef _Float16 f16x8 __attribute__((ext_vector_type(8)));
typedef float f32x4 __attribute__((ext_vector_type(4)));

// load 8 consecutive halfs (16B, aligned) -> two float4
__device__ __forceinline__ void ldx8h(const __half* p, float4& lo, float4& hi) {
    uint4 u = *(const uint4*)p;
    __half2 h0 = *(__half2*)&u.x;
    __half2 h1 = *(__half2*)&u.y;
    __half2 h2 = *(__half2*)&u.z;
    __half2 h3 = *(__half2*)&u.w;
    float2 a = __half22float2(h0);
    float2 b = __half22float2(h1);
    float2 c = __half22float2(h2);
    float2 d = __half22float2(h3);
    lo = make_float4(a.x, a.y, b.x, b.y);
    hi = make_float4(c.x, c.y, d.x, d.y);
}

// ---- K1: per-chunk coarse histogram (blocks [0,nchunks)) + MFMA GEMM ----
// GEMM: swapped-operand mfma -> each lane owns 4 consecutive features of one
// row: two 8B packed stores per tile (vs 16 scalar 2B). Stores RAW xw fp16;
// dinv scaling happens later in csr_kernel (which knows exact degrees free).
__global__ __launch_bounds__(256) void histgemm_kernel(
    const int* __restrict__ ei, int* __restrict__ ghist,
    const float* __restrict__ s, const float* __restrict__ W,
    __half* __restrict__ xwp, int E, int rows, int N, int nchunks) {
    __shared__ float Wf[32][33];   // 4.2 KB; hist role reuses first 1 KB
    int tid = threadIdx.x;

    if ((int)blockIdx.x < nchunks) {
        int* lh = (int*)Wf;
        lh[tid] = 0;
        __syncthreads();
        int beg = blockIdx.x * SP_CH;
        int end = min(beg + SP_CH, E);
        for (int e = beg + tid; e < end; e += 256)
            atomicAdd(&lh[ei[E + e] >> BINW_SHIFT], 1);
        __syncthreads();
        ghist[(size_t)blockIdx.x * NB + tid] = lh[tid];
        return;
    }

    // ---- GEMM role ----
    {
        float4 wv = ((const float4*)W)[tid];
        int kk = tid >> 3, c4 = (tid & 7) * 4;
        Wf[kk][c4 + 0] = wv.x; Wf[kk][c4 + 1] = wv.y;
        Wf[kk][c4 + 2] = wv.z; Wf[kk][c4 + 3] = wv.w;
    }
    __syncthreads();

    int lane = tid & 63;
    int wid  = tid >> 6;          // 0..3
    int lrow = lane & 15;
    int kq   = lane >> 4;         // k-group 0..3
    int k0   = kq * 8;

    // b-frags hold W^T rows (used as the MFMA A operand)
    f16x8 b0, b1;
#pragma unroll
    for (int i = 0; i < 8; i++) {
        b0[i] = (_Float16)Wf[k0 + i][lrow];
        b1[i] = (_Float16)Wf[k0 + i][lrow + 16];
    }

    int rbase = ((int)blockIdx.x - nchunks) * 128 + wid * 32;
#pragma unroll
    for (int rt = 0; rt < 2; rt++) {
        int r = rbase + rt * 16 + lrow;
        f16x8 a;
        if (r < rows) {
            const float4* sp = (const float4*)(s + (size_t)r * 32 + k0);
            float4 u0 = sp[0], u1 = sp[1];
            a[0] = (_Float16)u0.x; a[1] = (_Float16)u0.y;
            a[2] = (_Float16)u0.z; a[3] = (_Float16)u0.w;
            a[4] = (_Float16)u1.x; a[5] = (_Float16)u1.y;
            a[6] = (_Float16)u1.z; a[7] = (_Float16)u1.w;
        } else {
#pragma unroll
            for (int i = 0; i < 8; i++) a[i] = (_Float16)0.f;
        }
        // Swapped operands: D = (W^T)(s^T) = (sW)^T.
        // D col (lane&15) = s-row in tile (== lrow), D row (kq*4+reg) = feature.
        f32x4 c0 = {0.f, 0.f, 0.f, 0.f};
        f32x4 c1 = {0.f, 0.f, 0.f, 0.f};
        c0 = __builtin_amdgcn_mfma_f32_16x16x32_f16(b0, a, c0, 0, 0, 0);
        c1 = __builtin_amdgcn_mfma_f32_16x16x32_f16(b1, a, c1, 0, 0, 0);
        if (r < rows) {
            int t = (r >= 3 * N) ? 3 : (r >= 2 * N) ? 2 : (r >= N) ? 1 : 0;
            int n = r - t * N;
            __half2 p0 = __floats2half2_rn(c0[0], c0[1]);
            __half2 p1 = __floats2half2_rn(c0[2], c0[3]);
            __half2 p2 = __floats2half2_rn(c1[0], c1[1]);
            __half2 p3 = __floats2half2_rn(c1[2], c1[3]);
            __half* dst = xwp + (size_t)n * 128 + t * 32;
            uint2 u0, u1;
            u0.x = *(unsigned int*)&p0; u0.y = *(unsigned int*)&p1;
            u1.x = *(unsigned int*)&p2; u1.y = *(unsigned int*)&p3;
            *(uint2*)(dst + kq * 4)      = u0;
            *(uint2*)(dst + 16 + kq * 4) = u1;
        }
    }
}

// ---- K2: transposed scan over chunks per bin ----
__global__ __launch_bounds__(512) void colscan_kernel(
    const int* __restrict__ ghist, int* __restrict__ ghist2,
    int* __restrict__ totals, int nchunks) {
    __shared__ int sc[512];
    int t = threadIdx.x;
    int b = blockIdx.x;
    int v = (t < nchunks) ? ghist[(size_t)t * NB + b] : 0;
    sc[t] = v;
    __syncthreads();
    for (int off = 1; off < 512; off <<= 1) {
        int tv = (t >= off) ? sc[t - off] : 0;
        __syncthreads();
        sc[t] += tv;
        __syncthreads();
    }
    if (t < nchunks) ghist2[(size_t)t * NB + b] = sc[t] - v;   // exclusive
    if (t == 511) totals[b] = sc[511];
}

// ---- K3: split with exact precomputed bases ----
__global__ __launch_bounds__(256) void split_kernel(
    const int* __restrict__ ei, const int* __restrict__ ghist,
    const int* __restrict__ ghist2, const int* __restrict__ totals,
    unsigned int* __restrict__ esorted, int E) {
    __shared__ int binB[NB], pscan[NB], gb[NB], pcur[NB];
    __shared__ unsigned int sbuf[SP_CH];
    int tid = threadIdx.x;
    int bid = blockIdx.x;

    int tot = totals[tid];
    binB[tid] = tot;
    __syncthreads();
    for (int off = 1; off < 256; off <<= 1) {
        int t = (tid >= off) ? binB[tid - off] : 0;
        __syncthreads();
        binB[tid] += t;
        __syncthreads();
    }
    int v = ghist[(size_t)bid * NB + tid];
    pscan[tid] = v;
    __syncthreads();
    for (int off = 1; off < 256; off <<= 1) {
        int t = (tid >= off) ? pscan[tid - off] : 0;
        __syncthreads();
        pscan[tid] += t;
        __syncthreads();
    }
    int pexcl = pscan[tid] - v;
    pscan[tid] = pexcl;
    pcur[tid] = pexcl;
    gb[tid] = (binB[tid] - tot) + ghist2[(size_t)bid * NB + tid] - pexcl;
    __syncthreads();

    int beg = bid * SP_CH;
    int end = min(beg + SP_CH, E);
    int cnt = end - beg;
    for (int e = beg + tid; e < end; e += 256) {
        int sx = ei[e];
        int dx = ei[E + e];
        unsigned int pk = (unsigned int)sx | ((unsigned int)dx << 16);
        int b = dx >> BINW_SHIFT;
        int p = atomicAdd(&pcur[b], 1);
        sbuf[p] = pk;
    }
    __syncthreads();
    for (int idx = tid; idx < cnt; idx += 256) {
        unsigned int e = sbuf[idx];
        int b = e >> 24;                 // dst>>8 (dst in bits 16..31)
        esorted[gb[b] + idx] = e;
    }
}

// ---- K4: per-bin exact CSR + in-place dinv-scaling of this bin's xwp slab.
// Bin owns nodes [bin*256, bin*256+256) -> xwp slab is a contiguous 64 KB
// region; scaling is fully coalesced (uint4/lane, 16 iters). ----
__global__ __launch_bounds__(256) void csr_kernel(
    const int* __restrict__ totals, const unsigned int* __restrict__ esorted,
    int* __restrict__ rec, int* __restrict__ offs, int* __restrict__ deg,
    float* __restrict__ dinv, __half* __restrict__ xwp, int N) {
    __shared__ int lh[NB], sc[NB], loff[NB], lcur[NB];
    __shared__ float sdi[NB];
    __shared__ int s_ebeg, s_cnt;
    int bin = blockIdx.x;
    int tid = threadIdx.x;
    sc[tid] = totals[tid];
    lh[tid] = 0;
    __syncthreads();
    for (int off = 1; off < 256; off <<= 1) {
        int t = (tid >= off) ? sc[tid - off] : 0;
        __syncthreads();
        sc[tid] += t;
        __syncthreads();
    }
    if (tid == 0) {
        int e0 = bin ? sc[bin - 1] : 0;
        s_ebeg = e0;
        s_cnt = sc[bin] - e0;
    }
    __syncthreads();
    int ebeg = s_ebeg;
    int cnt = s_cnt;
    int gbase = ((ebeg + 3) & ~3) + PAD_PER_BIN * bin;
    for (int i = tid; i < cnt; i += 256)
        atomicAdd(&lh[(esorted[ebeg + i] >> 16) & 255], 1);
    __syncthreads();
    sdi[tid] = rsqrtf((float)lh[tid] + 1.0f);
    int padded = (lh[tid] + 3) & ~3;
    sc[tid] = padded;
    __syncthreads();
    for (int off = 1; off < 256; off <<= 1) {
        int t = (tid >= off) ? sc[tid - off] : 0;
        __syncthreads();
        sc[tid] += t;
        __syncthreads();
    }
    loff[tid] = sc[tid] - padded;
    lcur[tid] = 0;
    __syncthreads();
    for (int i = tid; i < cnt; i += 256) {
        unsigned int e = esorted[ebeg + i];
        int ln = (e >> 16) & 255;
        int p = atomicAdd(&lcur[ln], 1);
        rec[gbase + loff[ln] + p] = (int)(e & 0xFFFFu);
    }
    int n = (bin << BINW_SHIFT) + tid;
    if (n < N) {
        offs[n] = gbase + loff[tid];
        deg[n] = lh[tid];
        dinv[n] = sdi[tid];
    }
    // ---- epilogue: xws = dinv .* xw for this bin's slab (coalesced) ----
    {
        int hbase = bin << 15;                       // bin*32768 halfs
        int limit = min(32768, N * 128 - hbase);     // valid halfs (mult of 128)
        __half* slab = xwp + hbase;
        for (int i = tid; i * 8 < limit; i += 256) {
            float di = sdi[i >> 4];                  // node = (i*8)/128
            uint4 u = *(uint4*)(slab + i * 8);
            __half2 h0 = *(__half2*)&u.x;
            __half2 h1 = *(__half2*)&u.y;
            __half2 h2 = *(__half2*)&u.z;
            __half2 h3 = *(__half2*)&u.w;
            float2 f0 = __half22float2(h0);
            float2 f1 = __half22float2(h1);
            float2 f2 = __half22float2(h2);
            float2 f3 = __half22float2(h3);
            h0 = __floats2half2_rn(f0.x * di, f0.y * di);
            h1 = __floats2half2_rn(f1.x * di, f1.y * di);
            h2 = __floats2half2_rn(f2.x * di, f2.y * di);
            h3 = __floats2half2_rn(f3.x * di, f3.y * di);
            u.x = *(unsigned int*)&h0;
            u.y = *(unsigned int*)&h1;
            u.z = *(unsigned int*)&h2;
            u.w = *(unsigned int*)&h3;
            *(uint4*)(slab + i * 8) = u;
        }
    }
}

// ---- K5: fused gather over PRE-SCALED xwp: acc = dinv[n]*(sum rows + self),
// no per-edge dinv loads (VMEM/8-edges: 18 -> 10), adds not FMAs. ----
__global__ __launch_bounds__(256) void gather_kernel(
    const int* __restrict__ rec, const int* __restrict__ offs,
    const int* __restrict__ deg, const __half* __restrict__ xwp,
    const float* __restrict__ dinv, const float* __restrict__ z,
    float* __restrict__ out, int N) {
    int gid = blockIdx.x * 256 + threadIdx.x;
    int n = gid >> 4;
    if (n >= N) return;
    int wl = threadIdx.x & 63;
    int g = wl >> 4;          // node slot in wave (0..3)
    int l = wl & 15;          // lane within node
    long lofs = (long)l * 8;  // offset in halfs (16B per lane)

    float dn = dinv[n];
    int beg = offs[n];        // multiple of 4 -> int4-aligned
    int cntn = deg[n];

    float4 aLo = make_float4(0.f, 0.f, 0.f, 0.f);
    float4 aHi = make_float4(0.f, 0.f, 0.f, 0.f);
    int i = 0;
    for (; i + 8 <= cntn; i += 8) {
        int4 sa = *(const int4*)(rec + beg + i);
        int4 sb = *(const int4*)(rec + beg + i + 4);
        float4 l0, h0, l1, h1, l2, h2, l3, h3;
        float4 l4, h4, l5, h5, l6, h6, l7, h7;
        ldx8h(xwp + (long)sa.x * 128 + lofs, l0, h0);
        ldx8h(xwp + (long)sa.y * 128 + lofs, l1, h1);
        ldx8h(xwp + (long)sa.z * 128 + lofs, l2, h2);
        ldx8h(xwp + (long)sa.w * 128 + lofs, l3, h3);
        ldx8h(xwp + (long)sb.x * 128 + lofs, l4, h4);
        ldx8h(xwp + (long)sb.y * 128 + lofs, l5, h5);
        ldx8h(xwp + (long)sb.z * 128 + lofs, l6, h6);
        ldx8h(xwp + (long)sb.w * 128 + lofs, l7, h7);
        aLo.x += (l0.x + l1.x) + (l2.x + l3.x) + (l4.x + l5.x) + (l6.x + l7.x);
        aLo.y += (l0.y + l1.y) + (l2.y + l3.y) + (l4.y + l5.y) + (l6.y + l7.y);
        aLo.z += (l0.z + l1.z) + (l2.z + l3.z) + (l4.z + l5.z) + (l6.z + l7.z);
        aLo.w += (l0.w + l1.w) + (l2.w + l3.w) + (l4.w + l5.w) + (l6.w + l7.w);
        aHi.x += (h0.x + h1.x) + (h2.x + h3.x) + (h4.x + h5.x) + (h6.x + h7.x);
        aHi.y += (h0.y + h1.y) + (h2.y + h3.y) + (h4.y + h5.y) + (h6.y + h7.y);
        aHi.z += (h0.z + h1.z) + (h2.z + h3.z) + (h4.z + h5.z) + (h6.z + h7.z);
        aHi.w += (h0.w + h1.w) + (h2.w + h3.w) + (h4.w + h5.w) + (h6.w + h7.w);
    }
    for (; i < cntn; i += 4) {
        int4 s4 = *(const int4*)(rec + beg + i);
        int rem = cntn - i;
        int i0 = s4.x;
        int i1 = (rem > 1) ? s4.y : i0;
        int i2 = (rem > 2) ? s4.z : i0;
        int i3 = (rem > 3) ? s4.w : i0;
        float w1 = (rem > 1) ? 1.f : 0.f;
        float w2 = (rem > 2) ? 1.f : 0.f;
        float w3 = (rem > 3) ? 1.f : 0.f;
        float4 l0, h0, l1, h1, l2, h2, l3, h3;
        ldx8h(xwp + (long)i0 * 128 + lofs, l0, h0);
        ldx8h(xwp + (long)i1 * 128 + lofs, l1, h1);
        ldx8h(xwp + (long)i2 * 128 + lofs, l2, h2);
        ldx8h(xwp + (long)i3 * 128 + lofs, l3, h3);
        aLo.x += l0.x + w1 * l1.x + w2 * l2.x + w3 * l3.x;
        aLo.y += l0.y + w1 * l1.y + w2 * l2.y + w3 * l3.y;
        aLo.z += l0.z + w1 * l1.z + w2 * l2.z + w3 * l3.z;
        aLo.w += l0.w + w1 * l1.w + w2 * l2.w + w3 * l3.w;
        aHi.x += h0.x + w1 * h1.x + w2 * h2.x + w3 * h3.x;
        aHi.y += h0.y + w1 * h1.y + w2 * h2.y + w3 * h3.y;
        aHi.z += h0.z + w1 * h1.z + w2 * h2.z + w3 * h3.z;
        aHi.w += h0.w + w1 * h1.w + w2 * h2.w + w3 * h3.w;
    }
    // self loop (pre-scaled: contributes dinv[n]^2 * xw[n] after final *dn)
    {
        float4 sl, sh;
        ldx8h(xwp + (long)n * 128 + lofs, sl, sh);
        aLo.x += sl.x; aLo.y += sl.y; aLo.z += sl.z; aLo.w += sl.w;
        aHi.x += sh.x; aHi.y += sh.y; aHi.z += sh.z; aHi.w += sh.w;
    }
    aLo.x *= dn; aLo.y *= dn; aLo.z *= dn; aLo.w *= dn;
    aHi.x *= dn; aHi.y *= dn; aHi.z *= dn; aHi.w *= dn;

    // Lane l holds halfs l*8..l*8+7 (t = l>>2, feature block (l&3)*8).
    float a8[8] = {aLo.x, aLo.y, aLo.z, aLo.w, aHi.x, aHi.y, aHi.z, aHi.w};
    float xs[TSTEPS][8];
    int base = g * 16;
#pragma unroll
    for (int t = 0; t < TSTEPS; t++) {
        int srcLane = base + t * 4 + l;
#pragma unroll
        for (int j = 0; j < 8; j++)
            xs[t][j] = __shfl(a8[j], srcLane, 64);
    }
    if (l < 4) {
        int colBase = n * 32 + l * 8;
        float v[8], y[8];
#pragma unroll
        for (int j = 0; j < 8; j++) {
            v[j] = 0.f;
            y[j] = (xs[0][j] + xs[1][j] + xs[2][j] + xs[3][j]) * 0.25f;
        }
#pragma unroll
        for (int t = 0; t < TSTEPS; t++) {
            float o[8];
#pragma unroll
            for (int j = 0; j < 8; j++) {
                v[j] += xs[t][j];
                o[j] = (v[j] >= 1.0f) ? 1.0f : 0.0f;
                v[j] -= o[j];
            }
            float* dst = out + (size_t)t * N * 32 + colBase;
            *(float4*)dst       = make_float4(o[0], o[1], o[2], o[3]);
            *(float4*)(dst + 4) = make_float4(o[4], o[5], o[6], o[7]);
        }
        float4 zv0 = *(const float4*)(z + colBase);
        float4 zv1 = *(const float4*)(z + colBase + 4);
        float* dst = out + (size_t)TSTEPS * N * 32 + colBase;
        *(float4*)dst       = make_float4(zv0.x + y[0], zv0.y + y[1], zv0.z + y[2], zv0.w + y[3]);
        *(float4*)(dst + 4) = make_float4(zv1.x + y[4], zv1.y + y[5], zv1.z + y[6], zv1.w + y[7]);
    }
}

extern "C" void kernel_launch(void* const* d_in, const int* in_sizes, int n_in,
                              void* d_out, int out_size, void* d_ws, size_t ws_size,
                              hipStream_t stream) {
    const float* s_seq = (const float*)d_in[0];
    const float* z_seq = (const float*)d_in[1];
    const float* W     = (const float*)d_in[2];
    const int*   ei    = (const int*)d_in[3];
    float* out = (float*)d_out;

    int N = in_sizes[1] / DIM;   // 50000
    int E = in_sizes[3] / 2;     // 800000
    int rows = TSTEPS * N;       // 200000
    int nb = (N + 255) >> BINW_SHIFT;        // 196
    int nchunks = (E + SP_CH - 1) / SP_CH;   // 391

    char* w = (char*)d_ws;
    __half* xwp           = (__half*)w;       w += (size_t)rows * DIM * 2;   // 12.8 MB
    unsigned int* esorted = (unsigned int*)w; w += (size_t)E * 4;            // 3.2 MB
    int*   rec    = (int*)w;  w += ((size_t)E + PAD_PER_BIN * nb + 16) * 4;  // 3.8 MB
    int*   offs   = (int*)w;  w += (size_t)N * 4;
    int*   deg    = (int*)w;  w += (size_t)N * 4;
    float* dinv   = (float*)w; w += (size_t)N * 4;
    int*   ghist  = (int*)w;  w += (size_t)nchunks * NB * 4;                 // 400 KB
    int*   ghist2 = (int*)w;  w += (size_t)nchunks * NB * 4;                 // 400 KB
    int*   totals = (int*)w;  w += NB * 4;

    int xwBlocks = (rows + 127) / 128;   // 1563
    histgemm_kernel<<<nchunks + xwBlocks, 256, 0, stream>>>(
        ei, ghist, s_seq, W, xwp, E, rows, N, nchunks);
    colscan_kernel<<<NB, 512, 0, stream>>>(ghist, ghist2, totals, nchunks);
    split_kernel<<<nchunks, 256, 0, stream>>>(ei, ghist, ghist2, totals, esorted, E);
    csr_kernel<<<nb, 256, 0, stream>>>(totals, esorted, rec, offs, deg, dinv, xwp, N);
    gather_kernel<<<(N * 16 + 255) / 256, 256, 0, stream>>>(rec, offs, deg, xwp,
                                                            dinv, z_seq, out, N);
}

// Round 8
// 151.127 us; speedup vs baseline: 1.2431x; 1.0206x over previous
//
#include <hip/hip_runtime.h>
#include <hip/hip_fp16.h>

#define TSTEPS 4
#define DIM 32
#define BINW_SHIFT 8          // 256 nodes per coarse bin
#define NB 256                // bins (actual 196, rest zero)
#define SP_CH 2048            // edges per chunk
#define NCHP 400              // padded chunk-stride for ghistT rows
#define PAD_PER_BIN 772       // worst-case rec padding per bin (256*3 + 4)

typedef _Float16 f16x8 __attribute__((ext_vector_type(8)));
typedef float f32x4 __attribute__((ext_vector_type(4)));

// load 8 consecutive halfs (16B, aligned) -> two float4
__device__ __forceinline__ void ldx8h(const __half* p, float4& lo, float4& hi) {
    uint4 u = *(const uint4*)p;
    __half2 h0 = *(__half2*)&u.x;
    __half2 h1 = *(__half2*)&u.y;
    __half2 h2 = *(__half2*)&u.z;
    __half2 h3 = *(__half2*)&u.w;
    float2 a = __half22float2(h0);
    float2 b = __half22float2(h1);
    float2 c = __half22float2(h2);
    float2 d = __half22float2(h3);
    lo = make_float4(a.x, a.y, b.x, b.y);
    hi = make_float4(c.x, c.y, d.x, d.y);
}

// ---- K1: per-chunk coarse histogram -> ghistT[bin][chunk] (transposed so
// colscan loads coalesce; scattered stores here are fire-and-forget). ----
__global__ __launch_bounds__(256) void hist_kernel(
    const int* __restrict__ ei, int* __restrict__ ghistT, int E) {
    __shared__ int lh[NB];
    int tid = threadIdx.x;
    lh[tid] = 0;
    __syncthreads();
    int beg = blockIdx.x * SP_CH;
    int end = min(beg + SP_CH, E);
    for (int e = beg + tid; e < end; e += 256)
        atomicAdd(&lh[ei[E + e] >> BINW_SHIFT], 1);
    __syncthreads();
    ghistT[tid * NCHP + blockIdx.x] = lh[tid];
}

// ---- K2: per-bin exclusive scan over chunks (coalesced row loads).
// ghist2[c][b] = exclusive within-bin base of chunk c; totals[b]. ----
__global__ __launch_bounds__(512) void colscan_kernel(
    const int* __restrict__ ghistT, int* __restrict__ ghist2,
    int* __restrict__ totals, int nchunks) {
    __shared__ int sc[512];
    int t = threadIdx.x;
    int b = blockIdx.x;
    int v = (t < nchunks) ? ghistT[b * NCHP + t] : 0;
    sc[t] = v;
    __syncthreads();
    for (int off = 1; off < 512; off <<= 1) {
        int tv = (t >= off) ? sc[t - off] : 0;
        __syncthreads();
        sc[t] += tv;
        __syncthreads();
    }
    if (t < nchunks) ghist2[(size_t)t * NB + b] = sc[t] - v;   // exclusive
    if (t == 511) totals[b] = sc[511];
}

// ---- K3: fused split (blocks [0,nchunks)) + MFMA GEMM (rest).
// Split: ONE scan (binScan) + ONE edge pass scattering DIRECTLY to exact
// precomputed global windows (no sbuf, no pscan, no copy-out). Block 0
// publishes binScanG for csr. GEMM role: R7-proven swapped-operand MFMA. ----
__global__ __launch_bounds__(256) void splitgemm_kernel(
    const int* __restrict__ ei, const int* __restrict__ ghist2,
    const int* __restrict__ totals, unsigned int* __restrict__ esorted,
    int* __restrict__ binScanG,
    const float* __restrict__ s, const float* __restrict__ W,
    __half* __restrict__ xwp, int E, int rows, int N, int nchunks) {
    __shared__ __align__(16) char smem[4352];   // GEMM Wf = 4224 B; split 3 KB
    int tid = threadIdx.x;

    if ((int)blockIdx.x < nchunks) {
        int* sBS  = (int*)smem;            // 256 ints
        int* gb   = (int*)(smem + 1024);   // 256 ints
        int* lcur = (int*)(smem + 2048);   // 256 ints
        int bid = blockIdx.x;
        int tot = totals[tid];
        sBS[tid] = tot;
        __syncthreads();
        for (int off = 1; off < 256; off <<= 1) {
            int t = (tid >= off) ? sBS[tid - off] : 0;
            __syncthreads();
            sBS[tid] += t;
            __syncthreads();
        }
        if (bid == 0) binScanG[tid] = sBS[tid];   // inclusive scan of totals
        gb[tid] = (sBS[tid] - tot) + ghist2[(size_t)bid * NB + tid];
        lcur[tid] = 0;
        __syncthreads();
        int beg = bid * SP_CH;
        int end = min(beg + SP_CH, E);
        for (int e = beg + tid; e < end; e += 256) {
            int sx = ei[e];
            int dx = ei[E + e];
            unsigned int pk = (unsigned int)sx | ((unsigned int)dx << 16);
            int b = dx >> BINW_SHIFT;
            int p = atomicAdd(&lcur[b], 1);
            esorted[gb[b] + p] = pk;
        }
        return;
    }

    // ---- GEMM role (R7-proven) ----
    float (*Wf)[33] = (float(*)[33])smem;
    {
        float4 wv = ((const float4*)W)[tid];
        int kk = tid >> 3, c4 = (tid & 7) * 4;
        Wf[kk][c4 + 0] = wv.x; Wf[kk][c4 + 1] = wv.y;
        Wf[kk][c4 + 2] = wv.z; Wf[kk][c4 + 3] = wv.w;
    }
    __syncthreads();

    int lane = tid & 63;
    int wid  = tid >> 6;          // 0..3
    int lrow = lane & 15;
    int kq   = lane >> 4;         // k-group 0..3
    int k0   = kq * 8;

    f16x8 b0, b1;
#pragma unroll
    for (int i = 0; i < 8; i++) {
        b0[i] = (_Float16)Wf[k0 + i][lrow];
        b1[i] = (_Float16)Wf[k0 + i][lrow + 16];
    }

    int rbase = ((int)blockIdx.x - nchunks) * 128 + wid * 32;
#pragma unroll
    for (int rt = 0; rt < 2; rt++) {
        int r = rbase + rt * 16 + lrow;
        f16x8 a;
        if (r < rows) {
            const float4* sp = (const float4*)(s + (size_t)r * 32 + k0);
            float4 u0 = sp[0], u1 = sp[1];
            a[0] = (_Float16)u0.x; a[1] = (_Float16)u0.y;
            a[2] = (_Float16)u0.z; a[3] = (_Float16)u0.w;
            a[4] = (_Float16)u1.x; a[5] = (_Float16)u1.y;
            a[6] = (_Float16)u1.z; a[7] = (_Float16)u1.w;
        } else {
#pragma unroll
            for (int i = 0; i < 8; i++) a[i] = (_Float16)0.f;
        }
        // Swapped operands: D = (W^T)(s^T) = (sW)^T.
        f32x4 c0 = {0.f, 0.f, 0.f, 0.f};
        f32x4 c1 = {0.f, 0.f, 0.f, 0.f};
        c0 = __builtin_amdgcn_mfma_f32_16x16x32_f16(b0, a, c0, 0, 0, 0);
        c1 = __builtin_amdgcn_mfma_f32_16x16x32_f16(b1, a, c1, 0, 0, 0);
        if (r < rows) {
            int t = (r >= 3 * N) ? 3 : (r >= 2 * N) ? 2 : (r >= N) ? 1 : 0;
            int n = r - t * N;
            __half2 p0 = __floats2half2_rn(c0[0], c0[1]);
            __half2 p1 = __floats2half2_rn(c0[2], c0[3]);
            __half2 p2 = __floats2half2_rn(c1[0], c1[1]);
            __half2 p3 = __floats2half2_rn(c1[2], c1[3]);
            __half* dst = xwp + (size_t)n * 128 + t * 32;
            uint2 u0, u1;
            u0.x = *(unsigned int*)&p0; u0.y = *(unsigned int*)&p1;
            u1.x = *(unsigned int*)&p2; u1.y = *(unsigned int*)&p3;
            *(uint2*)(dst + kq * 4)      = u0;
            *(uint2*)(dst + 16 + kq * 4) = u1;
        }
    }
}

// ---- K4: per-bin exact CSR @512 threads (halved passes) + slab dinv-scale.
// Bin extents from binScanG (no scan preamble). ----
__global__ __launch_bounds__(512) void csr_kernel(
    const int* __restrict__ binScanG, const unsigned int* __restrict__ esorted,
    int* __restrict__ rec, int* __restrict__ offs, int* __restrict__ deg,
    float* __restrict__ dinv, __half* __restrict__ xwp, int N) {
    __shared__ int lh[NB], sc[NB], loff[NB], lcur[NB];
    __shared__ float sdi[NB];
    int bin = blockIdx.x;
    int tid = threadIdx.x;
    int e0 = bin ? binScanG[bin - 1] : 0;
    int e1 = binScanG[bin];
    int ebeg = e0;
    int cnt = e1 - e0;
    if (tid < NB) lh[tid] = 0;
    __syncthreads();
    int gbase = ((ebeg + 3) & ~3) + PAD_PER_BIN * bin;
    for (int i = tid; i < cnt; i += 512)
        atomicAdd(&lh[(esorted[ebeg + i] >> 16) & 255], 1);
    __syncthreads();
    int padded = 0;
    if (tid < NB) {
        sdi[tid] = rsqrtf((float)lh[tid] + 1.0f);
        padded = (lh[tid] + 3) & ~3;
        sc[tid] = padded;
    }
    __syncthreads();
    for (int off = 1; off < 256; off <<= 1) {
        int t = (tid >= off && tid < NB) ? sc[tid - off] : 0;
        __syncthreads();
        if (tid < NB) sc[tid] += t;
        __syncthreads();
    }
    if (tid < NB) {
        loff[tid] = sc[tid] - padded;
        lcur[tid] = 0;
    }
    __syncthreads();
    for (int i = tid; i < cnt; i += 512) {
        unsigned int e = esorted[ebeg + i];
        int ln = (e >> 16) & 255;
        int p = atomicAdd(&lcur[ln], 1);
        rec[gbase + loff[ln] + p] = (int)(e & 0xFFFFu);
    }
    int n = (bin << BINW_SHIFT) + tid;
    if (tid < NB && n < N) {
        offs[n] = gbase + loff[tid];
        deg[n] = lh[tid];
        dinv[n] = sdi[tid];
    }
    // ---- epilogue: xws = dinv .* xw for this bin's 64 KB slab (coalesced) ----
    {
        int hbase = bin << 15;                       // bin*32768 halfs
        int limit = min(32768, N * 128 - hbase);
        __half* slab = xwp + hbase;
        for (int i = tid; i * 8 < limit; i += 512) {
            float di = sdi[i >> 4];                  // node = (i*8)/128
            uint4 u = *(uint4*)(slab + i * 8);
            __half2 h0 = *(__half2*)&u.x;
            __half2 h1 = *(__half2*)&u.y;
            __half2 h2 = *(__half2*)&u.z;
            __half2 h3 = *(__half2*)&u.w;
            float2 f0 = __half22float2(h0);
            float2 f1 = __half22float2(h1);
            float2 f2 = __half22float2(h2);
            float2 f3 = __half22float2(h3);
            h0 = __floats2half2_rn(f0.x * di, f0.y * di);
            h1 = __floats2half2_rn(f1.x * di, f1.y * di);
            h2 = __floats2half2_rn(f2.x * di, f2.y * di);
            h3 = __floats2half2_rn(f3.x * di, f3.y * di);
            u.x = *(unsigned int*)&h0;
            u.y = *(unsigned int*)&h1;
            u.z = *(unsigned int*)&h2;
            u.w = *(unsigned int*)&h3;
            *(uint4*)(slab + i * 8) = u;
        }
    }
}

// ---- K5: fused gather over PRE-SCALED xwp (R7-proven, unchanged) ----
__global__ __launch_bounds__(256) void gather_kernel(
    const int* __restrict__ rec, const int* __restrict__ offs,
    const int* __restrict__ deg, const __half* __restrict__ xwp,
    const float* __restrict__ dinv, const float* __restrict__ z,
    float* __restrict__ out, int N) {
    int gid = blockIdx.x * 256 + threadIdx.x;
    int n = gid >> 4;
    if (n >= N) return;
    int wl = threadIdx.x & 63;
    int g = wl >> 4;          // node slot in wave (0..3)
    int l = wl & 15;          // lane within node
    long lofs = (long)l * 8;  // offset in halfs (16B per lane)

    float dn = dinv[n];
    int beg = offs[n];        // multiple of 4 -> int4-aligned
    int cntn = deg[n];

    float4 aLo = make_float4(0.f, 0.f, 0.f, 0.f);
    float4 aHi = make_float4(0.f, 0.f, 0.f, 0.f);
    int i = 0;
    for (; i + 8 <= cntn; i += 8) {
        int4 sa = *(const int4*)(rec + beg + i);
        int4 sb = *(const int4*)(rec + beg + i + 4);
        float4 l0, h0, l1, h1, l2, h2, l3, h3;
        float4 l4, h4, l5, h5, l6, h6, l7, h7;
        ldx8h(xwp + (long)sa.x * 128 + lofs, l0, h0);
        ldx8h(xwp + (long)sa.y * 128 + lofs, l1, h1);
        ldx8h(xwp + (long)sa.z * 128 + lofs, l2, h2);
        ldx8h(xwp + (long)sa.w * 128 + lofs, l3, h3);
        ldx8h(xwp + (long)sb.x * 128 + lofs, l4, h4);
        ldx8h(xwp + (long)sb.y * 128 + lofs, l5, h5);
        ldx8h(xwp + (long)sb.z * 128 + lofs, l6, h6);
        ldx8h(xwp + (long)sb.w * 128 + lofs, l7, h7);
        aLo.x += (l0.x + l1.x) + (l2.x + l3.x) + (l4.x + l5.x) + (l6.x + l7.x);
        aLo.y += (l0.y + l1.y) + (l2.y + l3.y) + (l4.y + l5.y) + (l6.y + l7.y);
        aLo.z += (l0.z + l1.z) + (l2.z + l3.z) + (l4.z + l5.z) + (l6.z + l7.z);
        aLo.w += (l0.w + l1.w) + (l2.w + l3.w) + (l4.w + l5.w) + (l6.w + l7.w);
        aHi.x += (h0.x + h1.x) + (h2.x + h3.x) + (h4.x + h5.x) + (h6.x + h7.x);
        aHi.y += (h0.y + h1.y) + (h2.y + h3.y) + (h4.y + h5.y) + (h6.y + h7.y);
        aHi.z += (h0.z + h1.z) + (h2.z + h3.z) + (h4.z + h5.z) + (h6.z + h7.z);
        aHi.w += (h0.w + h1.w) + (h2.w + h3.w) + (h4.w + h5.w) + (h6.w + h7.w);
    }
    for (; i < cntn; i += 4) {
        int4 s4 = *(const int4*)(rec + beg + i);
        int rem = cntn - i;
        int i0 = s4.x;
        int i1 = (rem > 1) ? s4.y : i0;
        int i2 = (rem > 2) ? s4.z : i0;
        int i3 = (rem > 3) ? s4.w : i0;
        float w1 = (rem > 1) ? 1.f : 0.f;
        float w2 = (rem > 2) ? 1.f : 0.f;
        float w3 = (rem > 3) ? 1.f : 0.f;
        float4 l0, h0, l1, h1, l2, h2, l3, h3;
        ldx8h(xwp + (long)i0 * 128 + lofs, l0, h0);
        ldx8h(xwp + (long)i1 * 128 + lofs, l1, h1);
        ldx8h(xwp + (long)i2 * 128 + lofs, l2, h2);
        ldx8h(xwp + (long)i3 * 128 + lofs, l3, h3);
        aLo.x += l0.x + w1 * l1.x + w2 * l2.x + w3 * l3.x;
        aLo.y += l0.y + w1 * l1.y + w2 * l2.y + w3 * l3.y;
        aLo.z += l0.z + w1 * l1.z + w2 * l2.z + w3 * l3.z;
        aLo.w += l0.w + w1 * l1.w + w2 * l2.w + w3 * l3.w;
        aHi.x += h0.x + w1 * h1.x + w2 * h2.x + w3 * h3.x;
        aHi.y += h0.y + w1 * h1.y + w2 * h2.y + w3 * h3.y;
        aHi.z += h0.z + w1 * h1.z + w2 * h2.z + w3 * h3.z;
        aHi.w += h0.w + w1 * h1.w + w2 * h2.w + w3 * h3.w;
    }
    // self loop (pre-scaled: contributes dinv[n]^2 * xw[n] after final *dn)
    {
        float4 sl, sh;
        ldx8h(xwp + (long)n * 128 + lofs, sl, sh);
        aLo.x += sl.x; aLo.y += sl.y; aLo.z += sl.z; aLo.w += sl.w;
        aHi.x += sh.x; aHi.y += sh.y; aHi.z += sh.z; aHi.w += sh.w;
    }
    aLo.x *= dn; aLo.y *= dn; aLo.z *= dn; aLo.w *= dn;
    aHi.x *= dn; aHi.y *= dn; aHi.z *= dn; aHi.w *= dn;

    // Lane l holds halfs l*8..l*8+7 (t = l>>2, feature block (l&3)*8).
    float a8[8] = {aLo.x, aLo.y, aLo.z, aLo.w, aHi.x, aHi.y, aHi.z, aHi.w};
    float xs[TSTEPS][8];
    int base = g * 16;
#pragma unroll
    for (int t = 0; t < TSTEPS; t++) {
        int srcLane = base + t * 4 + l;
#pragma unroll
        for (int j = 0; j < 8; j++)
            xs[t][j] = __shfl(a8[j], srcLane, 64);
    }
    if (l < 4) {
        int colBase = n * 32 + l * 8;
        float v[8], y[8];
#pragma unroll
        for (int j = 0; j < 8; j++) {
            v[j] = 0.f;
            y[j] = (xs[0][j] + xs[1][j] + xs[2][j] + xs[3][j]) * 0.25f;
        }
#pragma unroll
        for (int t = 0; t < TSTEPS; t++) {
            float o[8];
#pragma unroll
            for (int j = 0; j < 8; j++) {
                v[j] += xs[t][j];
                o[j] = (v[j] >= 1.0f) ? 1.0f : 0.0f;
                v[j] -= o[j];
            }
            float* dst = out + (size_t)t * N * 32 + colBase;
            *(float4*)dst       = make_float4(o[0], o[1], o[2], o[3]);
            *(float4*)(dst + 4) = make_float4(o[4], o[5], o[6], o[7]);
        }
        float4 zv0 = *(const float4*)(z + colBase);
        float4 zv1 = *(const float4*)(z + colBase + 4);
        float* dst = out + (size_t)TSTEPS * N * 32 + colBase;
        *(float4*)dst       = make_float4(zv0.x + y[0], zv0.y + y[1], zv0.z + y[2], zv0.w + y[3]);
        *(float4*)(dst + 4) = make_float4(zv1.x + y[4], zv1.y + y[5], zv1.z + y[6], zv1.w + y[7]);
    }
}

extern "C" void kernel_launch(void* const* d_in, const int* in_sizes, int n_in,
                              void* d_out, int out_size, void* d_ws, size_t ws_size,
                              hipStream_t stream) {
    const float* s_seq = (const float*)d_in[0];
    const float* z_seq = (const float*)d_in[1];
    const float* W     = (const float*)d_in[2];
    const int*   ei    = (const int*)d_in[3];
    float* out = (float*)d_out;

    int N = in_sizes[1] / DIM;   // 50000
    int E = in_sizes[3] / 2;     // 800000
    int rows = TSTEPS * N;       // 200000
    int nb = (N + 255) >> BINW_SHIFT;        // 196
    int nchunks = (E + SP_CH - 1) / SP_CH;   // 391

    char* w = (char*)d_ws;
    __half* xwp           = (__half*)w;       w += (size_t)rows * DIM * 2;   // 12.8 MB
    unsigned int* esorted = (unsigned int*)w; w += (size_t)E * 4;            // 3.2 MB
    int*   rec     = (int*)w;  w += ((size_t)E + PAD_PER_BIN * nb + 16) * 4; // 3.8 MB
    int*   offs    = (int*)w;  w += (size_t)N * 4;
    int*   deg     = (int*)w;  w += (size_t)N * 4;
    float* dinv    = (float*)w; w += (size_t)N * 4;
    int*   ghistT  = (int*)w;  w += (size_t)NB * NCHP * 4;                   // 400 KB
    int*   ghist2  = (int*)w;  w += (size_t)nchunks * NB * 4;                // 400 KB
    int*   totals  = (int*)w;  w += NB * 4;
    int*   binScanG = (int*)w; w += NB * 4;

    int xwBlocks = (rows + 127) / 128;   // 1563
    hist_kernel<<<nchunks, 256, 0, stream>>>(ei, ghistT, E);
    colscan_kernel<<<NB, 512, 0, stream>>>(ghistT, ghist2, totals, nchunks);
    splitgemm_kernel<<<nchunks + xwBlocks, 256, 0, stream>>>(
        ei, ghist2, totals, esorted, binScanG, s_seq, W, xwp, E, rows, N, nchunks);
    csr_kernel<<<nb, 512, 0, stream>>>(binScanG, esorted, rec, offs, deg, dinv,
                                       xwp, N);
    gather_kernel<<<(N * 16 + 255) / 256, 256, 0, stream>>>(rec, offs, deg, xwp,
                                                            dinv, z_seq, out, N);
}